// Round 10
// baseline (4117.637 us; speedup 1.0000x reference)
//
#include <hip/hip_runtime.h>

// ---------------------------------------------------------------------------
// GRUAgg: ragged groups -> dense [B,96,D] (timestamp-sorted, zero-padded head)
// -> 2-layer GRU (PyTorch gate order r,z,n) -> mean over 96 steps.
// B=2048, L=96, D=256, 3D=768, E=131072.
// Round-15: k_recur 2-blocks/CU restructure (k_xgemm = round-12, untouched).
//  Evidence: k_recur Occupancy 22% = ONE 8-wave block/CU (LDS 128KB);
//  barrier-locked MFMA-phase <-> gate-phase alternation leaves whichever
//  pipe idle (MfmaUtil 29 + VALUBusy 48, ~23% idle). Bank-conflict fix
//  (round-14) was neutral -> conflicts off critical path; swizzle kept.
//  Change: grid 512 x 4 groups/block. A-frag rows [0-3], C rows dup mod 4 ->
//  every lane holds all 4 rows of its col; ownership split so each thread
//  computes 2 gate-sets (grid VALU unchanged, MFMA issue 2x vs 29% util).
//  lBn DELETED (n1 = 6th compiler-managed weight array; L2 reloads proven
//  cheap r12/r13); LDS 128->40KB; launch_bounds(512,4) caps VGPR 128 ->
//  2 blocks/CU -> one block's MFMA overlaps the other's gate VALU.
// ---------------------------------------------------------------------------

typedef short bh8 __attribute__((ext_vector_type(8)));   // 8 bf16 in 4 VGPRs
typedef float f4  __attribute__((ext_vector_type(4)));   // MFMA accumulator
typedef unsigned int u4v __attribute__((ext_vector_type(4)));

#define NB 2048
#define LT 96
#define DF 256
#define NG 768

// h LDS frag layout: [kt(8)][region-swizzled lane][j(8)] bf16.
// element (row,col): q=(col>>3)&3; region=(col>>5)*64 + q*16 + (row^q);
// u16 index = region*8 + (col&7). rows 0..3 -> row^q in 0..3.
#define LHA(col, row) \
  (((((col) >> 5) * 64 + (((col) >> 3) & 3) * 16 + (((row) ^ (((col) >> 3) & 3)) & 15)) * 8) + ((col) & 7))

#define LGKM0()  asm volatile("s_waitcnt lgkmcnt(0)" ::: "memory")
#define SBAR()   __builtin_amdgcn_s_barrier()
#define SCHED0() __builtin_amdgcn_sched_barrier(0)

template <int N>
static __device__ __forceinline__ void vmw() {
  if constexpr (N == 0)      asm volatile("s_waitcnt vmcnt(0)" ::: "memory");
  else if constexpr (N == 1) asm volatile("s_waitcnt vmcnt(1)" ::: "memory");
  else if constexpr (N == 2) asm volatile("s_waitcnt vmcnt(2)" ::: "memory");
  else if constexpr (N == 3) asm volatile("s_waitcnt vmcnt(3)" ::: "memory");
  else if constexpr (N == 4) asm volatile("s_waitcnt vmcnt(4)" ::: "memory");
  else if constexpr (N == 5) asm volatile("s_waitcnt vmcnt(5)" ::: "memory");
  else if constexpr (N == 6) asm volatile("s_waitcnt vmcnt(6)" ::: "memory");
  else                       asm volatile("s_waitcnt vmcnt(7)" ::: "memory");
}

// async global->LDS, 16B per lane; LDS dest is wave-uniform base + lane*16.
static __device__ __forceinline__ void gl2lds16(const void* g, void* l) {
  __builtin_amdgcn_global_load_lds(
      (const __attribute__((address_space(1))) unsigned int*)g,
      (__attribute__((address_space(3))) unsigned int*)l, 16, 0, 0);
}

// Inline-asm loads (k_xgemm staging): immune to IR-level sinking. Every
// consumer sits below an explicit counted vmcnt + sched_barrier(0) fence.
static __device__ __forceinline__ void gld_b8(bh8& d, const unsigned short* p) {
  asm volatile("global_load_dwordx4 %0, %1, off" : "=&v"(d) : "v"(p));
}
static __device__ __forceinline__ void gld_i32(int& d, const int* p) {
  asm volatile("global_load_dword %0, %1, off" : "=&v"(d) : "v"(p));
}
static __device__ __forceinline__ void gld_pf16(f4* pf, const float* p) {
  asm volatile(
      "global_load_dwordx4 %0, %16, off\n\t"
      "global_load_dwordx4 %1, %16, off offset:16\n\t"
      "global_load_dwordx4 %2, %16, off offset:32\n\t"
      "global_load_dwordx4 %3, %16, off offset:48\n\t"
      "global_load_dwordx4 %4, %16, off offset:64\n\t"
      "global_load_dwordx4 %5, %16, off offset:80\n\t"
      "global_load_dwordx4 %6, %16, off offset:96\n\t"
      "global_load_dwordx4 %7, %16, off offset:112\n\t"
      "global_load_dwordx4 %8, %16, off offset:128\n\t"
      "global_load_dwordx4 %9, %16, off offset:144\n\t"
      "global_load_dwordx4 %10, %16, off offset:160\n\t"
      "global_load_dwordx4 %11, %16, off offset:176\n\t"
      "global_load_dwordx4 %12, %16, off offset:192\n\t"
      "global_load_dwordx4 %13, %16, off offset:208\n\t"
      "global_load_dwordx4 %14, %16, off offset:224\n\t"
      "global_load_dwordx4 %15, %16, off offset:240"
      : "=&v"(pf[0]), "=&v"(pf[1]), "=&v"(pf[2]), "=&v"(pf[3]),
        "=&v"(pf[4]), "=&v"(pf[5]), "=&v"(pf[6]), "=&v"(pf[7]),
        "=&v"(pf[8]), "=&v"(pf[9]), "=&v"(pf[10]), "=&v"(pf[11]),
        "=&v"(pf[12]), "=&v"(pf[13]), "=&v"(pf[14]), "=&v"(pf[15])
      : "v"(p));
}
static __device__ __forceinline__ void gld_pb8(u4v* pb, const unsigned short* p) {
  asm volatile(
      "global_load_dwordx4 %0, %8, off\n\t"
      "global_load_dwordx4 %1, %8, off offset:16\n\t"
      "global_load_dwordx4 %2, %8, off offset:32\n\t"
      "global_load_dwordx4 %3, %8, off offset:48\n\t"
      "global_load_dwordx4 %4, %8, off offset:64\n\t"
      "global_load_dwordx4 %5, %8, off offset:80\n\t"
      "global_load_dwordx4 %6, %8, off offset:96\n\t"
      "global_load_dwordx4 %7, %8, off offset:112"
      : "=&v"(pb[0]), "=&v"(pb[1]), "=&v"(pb[2]), "=&v"(pb[3]),
        "=&v"(pb[4]), "=&v"(pb[5]), "=&v"(pb[6]), "=&v"(pb[7])
      : "v"(p));
}

static __device__ __forceinline__ unsigned short f2b(float f) {
  union { float f; unsigned int u; } v; v.f = f;
  unsigned int r = v.u + 0x7fffu + ((v.u >> 16) & 1u);   // RNE
  return (unsigned short)(r >> 16);
}
static __device__ __forceinline__ float b2f(unsigned short s) {
  union { unsigned int u; float f; } v; v.u = ((unsigned int)s) << 16; return v.f;
}
static __device__ __forceinline__ unsigned int pk2(float a, float b) {
  return (unsigned int)f2b(a) | ((unsigned int)f2b(b) << 16);
}
static __device__ __forceinline__ float sigm(float x) { return 1.0f / (1.0f + __expf(-x)); }
static __device__ __forceinline__ float tanh_(float x) { return 2.0f / (1.0f + __expf(-2.0f * x)) - 1.0f; }

// --------------------------- group offsets/counts ---------------------------
__global__ void k_offsets(const int* __restrict__ idx, int E,
                          int* __restrict__ offs, int* __restrict__ cnt) {
  int b = blockIdx.x * blockDim.x + threadIdx.x;
  if (b >= NB) return;
  int lo = 0, hi = E;
  while (lo < hi) { int m = (lo + hi) >> 1; if (idx[m] < b) lo = m + 1; else hi = m; }
  int lb = lo;
  lo = lb; hi = E;
  while (lo < hi) { int m = (lo + hi) >> 1; if (idx[m] < b + 1) lo = m + 1; else hi = m; }
  offs[b] = lb;
  cnt[b] = lo - lb;
}

// ------------- per-group stable timestamp rank -> slot permutation ----------
__global__ void k_rank(const float* __restrict__ ts, const int* __restrict__ offs,
                       const int* __restrict__ cnt, int* __restrict__ perm) {
  __shared__ float sts[96];
  int b = blockIdx.x, j = threadIdx.x;
  int o = offs[b];
  int c = cnt[b]; if (c > 96) c = 96;
  if (j < 96) perm[b * 96 + j] = -1;
  if (j < c) sts[j] = ts[o + j];
  __syncthreads();
  if (j < c) {
    float tj = sts[j];
    int rank = 0;
    for (int k = 0; k < c; ++k) {
      float tk = sts[k];
      rank += (tk < tj) || (tk == tj && k < j);
    }
    int slot = (tj > 0.0f ? (96 - c) : 0) + rank;
    perm[b * 96 + slot] = o + j;
  }
}

// ------------- pack 4 weight matrices into MFMA B-fragment order ------------
// value(nt,kt,lane,j) = W[n][k], n = nt*16+(lane&15), k = kt*32+(lane>>4)*8+j
// layout: [mat(4)][nt(48)][kt(8)][lane(64)][j(8)] bf16
__global__ void k_packw(const float* __restrict__ w0, const float* __restrict__ w1,
                        const float* __restrict__ w2, const float* __restrict__ w3,
                        unsigned short* __restrict__ wfrag) {
  int t = blockIdx.x * blockDim.x + threadIdx.x;
  if (t >= 4 * 48 * 8 * 64) return;
  int m = t / 24576;
  int r = t % 24576;
  int nt = r / 512;
  int kt = (r / 64) & 7;
  int lane = r & 63;
  int n = nt * 16 + (lane & 15);
  int kb = kt * 32 + (lane >> 4) * 8;
  const float* W = (m == 0) ? w0 : (m == 1) ? w1 : (m == 2) ? w2 : w3;
  unsigned int o[4];
#pragma unroll
  for (int p = 0; p < 4; ++p)
    o[p] = pk2(W[n * 256 + kb + 2 * p], W[n * 256 + kb + 2 * p + 1]);
  uint4 v; v.x = o[0]; v.y = o[1]; v.z = o[2]; v.w = o[3];
  *(uint4*)&wfrag[(size_t)t * 8] = v;
}

// --------------------------- input-projection GEMM --------------------------
// Round-12 version (validated 163 us): asm-pinned staging, 2 barriers/slab,
// counted vmcnt(4) drain, descending physical slab order.
template <int AMODE>
__launch_bounds__(256, 2)
__global__ void k_xgemm(const float* __restrict__ Ax, const unsigned short* __restrict__ Ab,
                        const int* __restrict__ perm, int t0, int slabsTotal, int jbN,
                        const unsigned short* __restrict__ wfrag, const float* __restrict__ bias,
                        unsigned short* __restrict__ Cout) {
  __shared__ __align__(16) unsigned short lsmA[16640];  // A-frag: 32 regions x 65 x 8 bf16
  __shared__ __align__(16) float lsmS[8960];            // fp32 slab: 64 x 140

  const int tid = threadIdx.x;
  const int ntb = blockIdx.x % 6;
  const int jb  = blockIdx.x / 6;
  if (jb >= slabsTotal) return;
  const int w = tid >> 6, l = tid & 63, lm = l & 15, lq = l >> 4;

  const unsigned short* wfN = wfrag + (size_t)ntb * 32768;
  bh8 bf[2][8];
#pragma unroll
  for (int i = 0; i < 2; ++i)
#pragma unroll
    for (int kt = 0; kt < 8; ++kt)
      gld_b8(bf[i][kt], &wfN[(((2 * w + i) * 8 + kt) * 64 + l) * 8]);
  const float bias0 = bias[ntb * 128 + (2 * w + 0) * 16 + lm];
  const float bias1 = bias[ntb * 128 + (2 * w + 1) * 16 + lm];

  const int trow = tid >> 2, tp = tid & 3;
  const int msub = trow >> 4, rlm = trow & 15;

  f4 pf[16];      // AMODE 0 prefetch (fp32), asm-pinned
  u4v pb[8];      // AMODE 1 prefetch (bf16), asm-pinned

  auto src_of = [&](int s) -> int {   // plain load: PROLOGUE ONLY
    int row = (slabsTotal - 1 - s) * 64 + trow;
    int tt = row >> 11, g = row & 2047;
    return perm[g * 96 + t0 + tt];
  };
  auto issue_pf = [&](int s, int src) {
    if (AMODE == 0) {
      if (src >= 0) {
        gld_pf16(pf, Ax + (size_t)src * 256 + tp * 64);
      } else {
#pragma unroll
        for (int i = 0; i < 16; ++i) pf[i] = (f4){0.f, 0.f, 0.f, 0.f};
      }
    } else {
      int row = (slabsTotal - 1 - s) * 64 + trow;   // descending physical slab
      gld_pb8(pb, Ab + (size_t)row * 256 + tp * 64);
    }
  };
  auto write_afrag = [&]() {
    unsigned short* aN = lsmA;
#pragma unroll
    for (int kk = 0; kk < 2; ++kk)
#pragma unroll
      for (int rlq = 0; rlq < 4; ++rlq) {
        int kt = 2 * tp + kk;
        unsigned short* d = &aN[(((msub * 8 + kt) * 65) + rlq * 16 + rlm) * 8];
        if (AMODE == 0) {
          f4 f0 = pf[8 * kk + 2 * rlq], f1 = pf[8 * kk + 2 * rlq + 1];
          uint4 v;
          v.x = pk2(f0.x, f0.y); v.y = pk2(f0.z, f0.w);
          v.z = pk2(f1.x, f1.y); v.w = pk2(f1.z, f1.w);
          *(uint4*)d = v;
        } else {
          *(u4v*)d = pb[4 * kk + rlq];
        }
      }
  };

  // prologue
  int srcNxt = -1;
  {
    int srcCur = -1;
    if (AMODE == 0) {
      srcCur = src_of(jb);
      if (jb + jbN < slabsTotal) srcNxt = src_of(jb + jbN);
    }
    issue_pf(jb, srcCur);
  }
  vmw<0>(); SCHED0();
  write_afrag();
  LGKM0(); SBAR();

  for (int s = jb; s < slabsTotal; s += jbN) {
    const int snext = s + jbN;
    const bool hasNext = snext < slabsTotal;
    const bool hasNext2 = snext + jbN < slabsTotal;
    int srcN2 = -1;
    if (hasNext) issue_pf(snext, srcNxt);
    if (AMODE == 0 && hasNext2) {
      int row = (slabsTotal - 1 - (snext + jbN)) * 64 + trow;
      int tt2 = row >> 11, g = row & 2047;
      gld_i32(srcN2, &perm[g * 96 + t0 + tt2]);
    }

    // MFMA from lsmA
    f4 acc[4][2];
#pragma unroll
    for (int m = 0; m < 4; ++m)
#pragma unroll
      for (int n = 0; n < 2; ++n) acc[m][n] = (f4){0.f, 0.f, 0.f, 0.f};
#pragma unroll
    for (int kt = 0; kt < 8; ++kt) {
      bh8 a[4];
#pragma unroll
      for (int m = 0; m < 4; ++m) a[m] = *(const bh8*)&lsmA[(((m * 8 + kt) * 65) + l) * 8];
#pragma unroll
      for (int m = 0; m < 4; ++m) {
        acc[m][0] = __builtin_amdgcn_mfma_f32_16x16x32_bf16(a[m], bf[0][kt], acc[m][0], 0, 0, 0);
        acc[m][1] = __builtin_amdgcn_mfma_f32_16x16x32_bf16(a[m], bf[1][kt], acc[m][1], 0, 0, 0);
      }
    }

    // epilogue: acc + bias -> fp32 slab (swizzled: phys = col + 4*(col>>5))
#pragma unroll
    for (int m = 0; m < 4; ++m)
#pragma unroll
      for (int n = 0; n < 2; ++n) {
        int phys = 36 * w + 16 * n + lm;
        float bv = n ? bias1 : bias0;
#pragma unroll
        for (int r = 0; r < 4; ++r)
          lsmS[(m * 16 + lq * 4 + r) * 140 + phys] = acc[m][n][r] + bv;
      }
    LGKM0(); SBAR();

    // merged interval: C-store (reads lsmS) || write_afrag (writes lsmA)
    {
      const float* sp = &lsmS[trow * 140 + 36 * tp];
      unsigned short* cp = &Cout[((size_t)(slabsTotal - 1 - s) * 64 + trow) * NG + ntb * 128 + tp * 32];
#pragma unroll
      for (int i = 0; i < 4; ++i) {
        f4 v0 = *(const f4*)(sp + 8 * i), v1 = *(const f4*)(sp + 8 * i + 4);
        uint4 o;
        o.x = pk2(v0.x, v0.y); o.y = pk2(v0.z, v0.w);
        o.z = pk2(v1.x, v1.y); o.w = pk2(v1.z, v1.w);
        *(uint4*)(cp + 8 * i) = o;
      }
    }
    if (hasNext) {
      // counted drain: queue = [pf x16][perm x<=1][store x4] -> retire
      // pf+perm, leave the 4 C-stores in flight.
      vmw<4>(); SCHED0();
      write_afrag();
      if (AMODE == 0) srcNxt = hasNext2 ? srcN2 : -1;
      LGKM0(); SBAR();
    }
  }
}

// ------------------------------ recurrent core ------------------------------
// Round-15: 512 blocks x 4 groups, 8 waves. A-frag rows [0-3] stored once
// (C rows dup mod 4 -> every lane holds all 4 rows of its col). Ownership:
// lq0: col0 rows{0,1}; lq1: col0 rows{2,3}; lq2/lq3: col1 same -> 2 gate-
// sets/thread. n1 = 6th plain weight array (compiler-managed, L2 reloads).
// Staging: 6144 B/step = 384 threads (waves 0-5), 1 gl2lds16 each, 4 LDS
// buffers, distance 3. vm ops/step: waves 0-1: [h1out (LAYER0, tt>=1)] +
// 1 gl2lds; waves 2-5: 1 gl2lds; waves 6-7: none (their vmw is a no-op and
// the barrier publishes stagers' landed data).
// End-of-step wait target = gl2lds(tt+1) issued at step tt-2; N = vm ops
// issued after it:
//   waves0-1/L0: tt=0:2 tt=1:3 steady:4 Ta-3:3 Ta-2:2
//   waves0-1/L1: tt=0:2 tt=1:2 steady:2 Ta-3:1 Ta-2:0
//   waves2-5:    tt=0:2 tt=1:2 steady:2 Ta-3:1 Ta-2:0
// In-order retirement: compiler-inserted vm ops only make waits stricter.
#define RSTEP(TT, W01, W25, ISSUE, H1, WAIT)                                               \
  {                                                                                        \
    if (LAYER == 0 && (H1) && tid < 128) {                                                 \
      int rw_ = tid >> 5, c0_ = (tid & 31) * 8;                                            \
      uint4 hv_ = *(const uint4*)&lh[(TT) & 1][LHA(c0_, rw_)];                             \
      *(uint4*)&h1out[((size_t)((TT) - 1) * NB + g0 + rw_) * DF + c0_] = hv_;              \
    }                                                                                      \
    if (ISSUE) {                                                                           \
      const unsigned short* gp_ = xg + ((size_t)((TT) + 3) * NB + g0) * NG;                \
      if (tid < 384) gl2lds16(gp_ + (size_t)tid * 8, lxg[((TT) + 3) & 3] + 512 * w);       \
    }                                                                                      \
    f4 ar0 = (f4){0.f,0.f,0.f,0.f}, ar1 = (f4){0.f,0.f,0.f,0.f};                           \
    f4 az0 = (f4){0.f,0.f,0.f,0.f}, az1 = (f4){0.f,0.f,0.f,0.f};                           \
    f4 an0 = (f4){0.f,0.f,0.f,0.f}, an1 = (f4){0.f,0.f,0.f,0.f};                           \
    {                                                                                      \
      const unsigned short* hc_ = lh[(TT) & 1];                                            \
      _Pragma("unroll")                                                                    \
      for (int kt = 0; kt < 8; ++kt) {                                                     \
        bh8 a_ = *(const bh8*)&hc_[(kt * 64 + lrd) * 8];                                   \
        ar0 = __builtin_amdgcn_mfma_f32_16x16x32_bf16(a_, br0[kt], ar0, 0, 0, 0);          \
        ar1 = __builtin_amdgcn_mfma_f32_16x16x32_bf16(a_, br1[kt], ar1, 0, 0, 0);          \
        az0 = __builtin_amdgcn_mfma_f32_16x16x32_bf16(a_, bz0[kt], az0, 0, 0, 0);          \
        az1 = __builtin_amdgcn_mfma_f32_16x16x32_bf16(a_, bz1[kt], az1, 0, 0, 0);          \
        an0 = __builtin_amdgcn_mfma_f32_16x16x32_bf16(a_, bn0[kt], an0, 0, 0, 0);          \
        an1 = __builtin_amdgcn_mfma_f32_16x16x32_bf16(a_, bn1[kt], an1, 0, 0, 0);          \
      }                                                                                    \
    }                                                                                      \
    {                                                                                      \
      f4 aR = (lq < 2) ? ar0 : ar1;                                                        \
      f4 aZ = (lq < 2) ? az0 : az1;                                                        \
      f4 aN = (lq < 2) ? an0 : an1;                                                        \
      const unsigned short* xc_ = lxg[(TT) & 3];                                           \
      unsigned short* hn_ = lh[((TT) & 1) ^ 1];                                            \
      const int sel_ = (lq & 1);                                                           \
      _Pragma("unroll")                                                                    \
      for (int j = 0; j < 2; ++j) {                                                        \
        int row_ = rlow + j;                                                               \
        int base_ = row_ * NG + mycol;                                                     \
        float aRv_ = sel_ ? aR[j + 2] : aR[j];                                             \
        float aZv_ = sel_ ? aZ[j + 2] : aZ[j];                                             \
        float aNv_ = sel_ ? aN[j + 2] : aN[j];                                             \
        float xr_ = b2f(xc_[base_]);                                                       \
        float xz_ = b2f(xc_[base_ + 256]);                                                 \
        float xn_ = b2f(xc_[base_ + 512]);                                                 \
        float r_ = sigm(xr_ + aRv_ + bhr);                                                 \
        float z_ = sigm(xz_ + aZv_ + bhz);                                                 \
        float n_ = tanh_(xn_ + r_ * (aNv_ + bhn));                                         \
        float h_ = (1.f - z_) * n_ + z_ * hp[j]; hp[j] = h_;                               \
        hn_[LHA(mycol, row_)] = f2b(h_);                                                   \
        if (LAYER == 1) sm[j] += h_;                                                       \
      }                                                                                    \
    }                                                                                      \
    LGKM0();                                                                               \
    if (WAIT) {                                                                            \
      if (w < 2) { vmw<(W01)>(); } else if (w < 6) { vmw<(W25)>(); }                       \
    }                                                                                      \
    SBAR();                                                                                \
  }

template <int LAYER>
__launch_bounds__(512, 4)
__global__ void k_recur(const unsigned short* __restrict__ wf, const float* __restrict__ bhh,
                        const unsigned short* __restrict__ xg, int Ta,
                        float* __restrict__ hstate, int first, int save,
                        unsigned short* __restrict__ h1out,
                        float* __restrict__ sumstate, float* __restrict__ outp, int last) {
  __shared__ __align__(16) unsigned short lh[2][4096];    // 16 KB: h frags (rows 0-3 used)
  __shared__ __align__(16) unsigned short lxg[4][3072];   // 24 KB: xg slabs, 4-deep

  const int tid = threadIdx.x;
  const int w = tid >> 6, l = tid & 63, lm = l & 15, lq = l >> 4;
  const int g0 = blockIdx.x * 4;
  const int colA = w * 32 + lm;
  const int mycol = (lq < 2) ? colA : (colA + 16);   // quad-pair owns one col
  const int rlow = (lq & 1) * 2;                     // rows rlow, rlow+1
  // A-frag read region: lane needs real row l&3, k-sub q = l>>4:
  const int lrd = (l >> 4) * 16 + (((l & 3) ^ (l >> 4)) & 15);

  // 6 weight B-fragments, compiler-managed (resident or cheap L2 reloads).
  bh8 br0[8], br1[8], bz0[8], bz1[8], bn0[8], bn1[8];
#pragma unroll
  for (int kt = 0; kt < 8; ++kt) {
    br0[kt] = *(const bh8*)&wf[(((2 * w + 0) * 8 + kt) * 64 + l) * 8];
    br1[kt] = *(const bh8*)&wf[(((2 * w + 1) * 8 + kt) * 64 + l) * 8];
    bz0[kt] = *(const bh8*)&wf[(((16 + 2 * w) * 8 + kt) * 64 + l) * 8];
    bz1[kt] = *(const bh8*)&wf[(((17 + 2 * w) * 8 + kt) * 64 + l) * 8];
    bn0[kt] = *(const bh8*)&wf[(((32 + 2 * w) * 8 + kt) * 64 + l) * 8];
    bn1[kt] = *(const bh8*)&wf[(((33 + 2 * w) * 8 + kt) * 64 + l) * 8];
  }
  const float bhr = bhh[mycol];
  const float bhz = bhh[256 + mycol];
  const float bhn = bhh[512 + mycol];

  {  // zero both h buffers
    uint4 z; z.x = 0u; z.y = 0u; z.z = 0u; z.w = 0u;
    for (int i = tid; i < 1024; i += 512) ((uint4*)lh)[i] = z;
  }
  __syncthreads();

  float hp[2], sm[2];
#pragma unroll
  for (int j = 0; j < 2; ++j) {
    int row = rlow + j;
    float a = first ? 0.f : hstate[(size_t)(g0 + row) * DF + mycol];
    hp[j] = a;
    lh[0][LHA(mycol, row)] = f2b(a);
    if (LAYER == 1) sm[j] = (!first) ? sumstate[(size_t)(g0 + row) * DF + mycol] : 0.f;
  }
  __syncthreads();

  if (Ta >= 6) {
    // prologue: async-stage xg(0),xg(1),xg(2) into buffers 0,1,2
#pragma unroll
    for (int k = 0; k < 3; ++k) {
      const unsigned short* gp = xg + ((size_t)k * NB + g0) * NG;
      if (tid < 384) gl2lds16(gp + (size_t)tid * 8, lxg[k] + 512 * w);
    }
    // wait for buf0 (target = oldest load; newer: g(1),g(2) -> N=2)
    LGKM0();
    if (w < 6) { vmw<2>(); }
    SBAR();

    RSTEP(0, 2, 2, true, false, true);
    RSTEP(1, (LAYER == 0 ? 3 : 2), 2, true, true, true);
    for (int tt = 2; tt <= Ta - 4; ++tt) {
      RSTEP(tt, (LAYER == 0 ? 4 : 2), 2, true, true, true);
    }
    RSTEP(Ta - 3, (LAYER == 0 ? 3 : 1), 1, false, true, true);
    RSTEP(Ta - 2, (LAYER == 0 ? 2 : 0), 0, false, true, true);
    RSTEP(Ta - 1, 0, 0, false, true, false);
  } else {
    // generic fallback: conservative vmcnt(0) per step
#pragma unroll
    for (int k = 0; k < 3; ++k) {
      if (k < Ta) {
        const unsigned short* gp = xg + ((size_t)k * NB + g0) * NG;
        if (tid < 384) gl2lds16(gp + (size_t)tid * 8, lxg[k] + 512 * w);
      }
    }
    LGKM0(); vmw<0>(); SBAR();
    for (int tt = 0; tt < Ta; ++tt) {
      RSTEP(tt, 0, 0, (tt + 3 < Ta), (tt >= 1), (tt + 1 < Ta));
    }
  }

  // final h1out block (h(Ta-1) lives in lh[Ta&1])
  const unsigned short* lhf = lh[Ta & 1];
  if (LAYER == 0 && tid < 128) {
    int row = tid >> 5, c0 = (tid & 31) * 8;
    uint4 hv = *(const uint4*)&lhf[LHA(c0, row)];
    *(uint4*)&h1out[((size_t)(Ta - 1) * NB + g0 + row) * DF + c0] = hv;
  }
  if (save) {
#pragma unroll
    for (int j = 0; j < 2; ++j) {
      int row = rlow + j;
      hstate[(size_t)(g0 + row) * DF + mycol] = hp[j];
    }
  }
  if (LAYER == 1) {
    if (last) {
#pragma unroll
      for (int j = 0; j < 2; ++j) {
        int row = rlow + j;
        outp[(size_t)(g0 + row) * DF + mycol] = sm[j] * (1.0f / 96.0f);
      }
    } else {
#pragma unroll
      for (int j = 0; j < 2; ++j) {
        int row = rlow + j;
        sumstate[(size_t)(g0 + row) * DF + mycol] = sm[j];
      }
    }
  }
}

// ------------------------------- host launcher ------------------------------
extern "C" void kernel_launch(void* const* d_in, const int* in_sizes, int n_in,
                              void* d_out, int out_size, void* d_ws, size_t ws_size,
                              hipStream_t stream) {
  (void)n_in; (void)out_size;
  const float* x    = (const float*)d_in[0];
  const float* ts   = (const float*)d_in[1];
  const float* wih0 = (const float*)d_in[2];
  const float* whh0 = (const float*)d_in[3];
  const float* bih0 = (const float*)d_in[4];
  const float* bhh0 = (const float*)d_in[5];
  const float* wih1 = (const float*)d_in[6];
  const float* whh1 = (const float*)d_in[7];
  const float* bih1 = (const float*)d_in[8];
  const float* bhh1 = (const float*)d_in[9];
  const int*   idx  = (const int*)d_in[10];
  float* out = (float*)d_out;
  const int E = in_sizes[0] / DF;

  char* wsb = (char*)d_ws;
  size_t off = 0;
  auto carve = [&](size_t bytes) -> char* {
    off = (off + 255) & ~(size_t)255;
    char* p = wsb + off;
    off += bytes;
    return p;
  };
  int* offs = (int*)carve((size_t)NB * 4);
  int* cntp = (int*)carve((size_t)NB * 4);
  int* perm = (int*)carve((size_t)NB * LT * 4);
  unsigned short* wfrag = (unsigned short*)carve((size_t)4 * 196608 * 2);
  float* h0s  = (float*)carve((size_t)NB * DF * 4);
  float* h1s  = (float*)carve((size_t)NB * DF * 4);
  float* sums = (float*)carve((size_t)NB * DF * 4);
  size_t fixedBytes = off;

  const size_t perT = (size_t)NB * DF * 2 + 2 * (size_t)NB * NG * 2;  // 7,340,032 B
  int Tc = 1;
  if (ws_size > fixedBytes + 4096) {
    size_t t = (ws_size - fixedBytes - 4096) / perT;
    Tc = (int)(t > 96 ? 96 : (t < 1 ? 1 : t));
  }
  unsigned short* h1buf = (unsigned short*)carve((size_t)Tc * NB * DF * 2);
  unsigned short* xgA   = (unsigned short*)carve((size_t)Tc * NB * NG * 2);
  unsigned short* xgB   = (unsigned short*)carve((size_t)Tc * NB * NG * 2);

  k_offsets<<<8, 256, 0, stream>>>(idx, E, offs, cntp);
  k_rank<<<NB, 128, 0, stream>>>(ts, offs, cntp, perm);
  k_packw<<<384, 256, 0, stream>>>(wih0, whh0, wih1, whh1, wfrag);

  for (int t0 = 0; t0 < LT; t0 += Tc) {
    int Ta = (LT - t0 < Tc) ? (LT - t0) : Tc;
    int first = (t0 == 0);
    int save = (t0 + Ta < LT);
    int last = (t0 + Ta == LT);
    int slabs = Ta * 32;
    // jbN: persistent-block stride; 6*jbN blocks, all co-resident (2/CU)
    int jbN = slabs < 85 ? slabs : 85;
    // layer 0 input projection (gathered x, pads -> b_ih)
    k_xgemm<0><<<dim3(6 * jbN), 256, 0, stream>>>(
        x, (const unsigned short*)nullptr, perm, t0, slabs, jbN, wfrag, bih0, xgA);
    // layer 0 recurrence -> h1buf (512 blocks x 4 groups -> 2 blocks/CU)
    k_recur<0><<<512, 512, 0, stream>>>(
        wfrag + 1 * 196608, bhh0, xgA, Ta, h0s, first, save, h1buf,
        (float*)nullptr, (float*)nullptr, 0);
    // layer 1 input projection (dense h1)
    k_xgemm<1><<<dim3(6 * jbN), 256, 0, stream>>>(
        (const float*)nullptr, h1buf, (const int*)nullptr, 0, slabs, jbN,
        wfrag + 2 * 196608, bih1, xgB);
    // layer 1 recurrence -> mean accumulation / output
    k_recur<1><<<512, 512, 0, stream>>>(
        wfrag + 3 * 196608, bhh1, xgB, Ta, h1s, first, save,
        (unsigned short*)nullptr, sums, out, last);
  }
}

// Round 11
// 947.629 us; speedup vs baseline: 4.3452x; 4.3452x over previous
//
#include <hip/hip_runtime.h>

// ---------------------------------------------------------------------------
// GRUAgg: ragged groups -> dense [B,96,D] (timestamp-sorted, zero-padded head)
// -> 2-layer GRU (PyTorch gate order r,z,n) -> mean over 96 steps.
// B=2048, L=96, D=256, 3D=768, E=131072.
// Round-16 == revert to round-14 (948 us validated) after round-15's
// 2-blocks/CU restructure catastrophically regressed (4118 us):
//  launch_bounds(512,4) clamped VGPR to 64 -> zero weight residency ->
//  4.6 GB/dispatch W_hh refetch. Structural lesson: 2 blocks/CU needs
//  <=128 VGPR but the per-wave weight set is 160-192 regs -> occupancy
//  route to MFMA/VALU phase overlap is closed. Within-step wave skew
//  already overlaps the pipes (29% Mfma + 48% VALU simultaneous).
//  k_xgemm: round-12 version (asm-pinned staging, 2 barriers/slab, counted
//  vmcnt(4), descending slabs). k_recur: round-12 base + round-14 swizzled
//  LHA (single-half h writes, dup-at-read, XOR row^q banks).
// ---------------------------------------------------------------------------

typedef short bh8 __attribute__((ext_vector_type(8)));   // 8 bf16 in 4 VGPRs
typedef float f4  __attribute__((ext_vector_type(4)));   // MFMA accumulator
typedef unsigned int u4v __attribute__((ext_vector_type(4)));

#define NB 2048
#define LT 96
#define DF 256
#define NG 768

// h LDS frag layout: [kt(8)][region-swizzled lane][j(8)] bf16.
// element (row,col): q=(col>>3)&3; region=(col>>5)*64 + q*16 + (row^q);
// u16 index = region*8 + (col&7). Banks: ((row^q)%8)*4 -> spread over 32.
#define LHA(col, row) \
  (((((col) >> 5) * 64 + (((col) >> 3) & 3) * 16 + (((row) ^ (((col) >> 3) & 3)) & 15)) * 8) + ((col) & 7))

#define LGKM0()  asm volatile("s_waitcnt lgkmcnt(0)" ::: "memory")
#define SBAR()   __builtin_amdgcn_s_barrier()
#define SCHED0() __builtin_amdgcn_sched_barrier(0)

template <int N>
static __device__ __forceinline__ void vmw() {
  if constexpr (N == 0)      asm volatile("s_waitcnt vmcnt(0)" ::: "memory");
  else if constexpr (N == 1) asm volatile("s_waitcnt vmcnt(1)" ::: "memory");
  else if constexpr (N == 2) asm volatile("s_waitcnt vmcnt(2)" ::: "memory");
  else if constexpr (N == 3) asm volatile("s_waitcnt vmcnt(3)" ::: "memory");
  else if constexpr (N == 4) asm volatile("s_waitcnt vmcnt(4)" ::: "memory");
  else if constexpr (N == 5) asm volatile("s_waitcnt vmcnt(5)" ::: "memory");
  else if constexpr (N == 6) asm volatile("s_waitcnt vmcnt(6)" ::: "memory");
  else                       asm volatile("s_waitcnt vmcnt(7)" ::: "memory");
}

// async global->LDS, 16B per lane; LDS dest is wave-uniform base + lane*16.
static __device__ __forceinline__ void gl2lds16(const void* g, void* l) {
  __builtin_amdgcn_global_load_lds(
      (const __attribute__((address_space(1))) unsigned int*)g,
      (__attribute__((address_space(3))) unsigned int*)l, 16, 0, 0);
}

// Inline-asm loads (k_xgemm staging): immune to IR-level sinking. Every
// consumer sits below an explicit counted vmcnt + sched_barrier(0) fence.
static __device__ __forceinline__ void gld_b8(bh8& d, const unsigned short* p) {
  asm volatile("global_load_dwordx4 %0, %1, off" : "=&v"(d) : "v"(p));
}
static __device__ __forceinline__ void gld_i32(int& d, const int* p) {
  asm volatile("global_load_dword %0, %1, off" : "=&v"(d) : "v"(p));
}
static __device__ __forceinline__ void gld_pf16(f4* pf, const float* p) {
  asm volatile(
      "global_load_dwordx4 %0, %16, off\n\t"
      "global_load_dwordx4 %1, %16, off offset:16\n\t"
      "global_load_dwordx4 %2, %16, off offset:32\n\t"
      "global_load_dwordx4 %3, %16, off offset:48\n\t"
      "global_load_dwordx4 %4, %16, off offset:64\n\t"
      "global_load_dwordx4 %5, %16, off offset:80\n\t"
      "global_load_dwordx4 %6, %16, off offset:96\n\t"
      "global_load_dwordx4 %7, %16, off offset:112\n\t"
      "global_load_dwordx4 %8, %16, off offset:128\n\t"
      "global_load_dwordx4 %9, %16, off offset:144\n\t"
      "global_load_dwordx4 %10, %16, off offset:160\n\t"
      "global_load_dwordx4 %11, %16, off offset:176\n\t"
      "global_load_dwordx4 %12, %16, off offset:192\n\t"
      "global_load_dwordx4 %13, %16, off offset:208\n\t"
      "global_load_dwordx4 %14, %16, off offset:224\n\t"
      "global_load_dwordx4 %15, %16, off offset:240"
      : "=&v"(pf[0]), "=&v"(pf[1]), "=&v"(pf[2]), "=&v"(pf[3]),
        "=&v"(pf[4]), "=&v"(pf[5]), "=&v"(pf[6]), "=&v"(pf[7]),
        "=&v"(pf[8]), "=&v"(pf[9]), "=&v"(pf[10]), "=&v"(pf[11]),
        "=&v"(pf[12]), "=&v"(pf[13]), "=&v"(pf[14]), "=&v"(pf[15])
      : "v"(p));
}
static __device__ __forceinline__ void gld_pb8(u4v* pb, const unsigned short* p) {
  asm volatile(
      "global_load_dwordx4 %0, %8, off\n\t"
      "global_load_dwordx4 %1, %8, off offset:16\n\t"
      "global_load_dwordx4 %2, %8, off offset:32\n\t"
      "global_load_dwordx4 %3, %8, off offset:48\n\t"
      "global_load_dwordx4 %4, %8, off offset:64\n\t"
      "global_load_dwordx4 %5, %8, off offset:80\n\t"
      "global_load_dwordx4 %6, %8, off offset:96\n\t"
      "global_load_dwordx4 %7, %8, off offset:112"
      : "=&v"(pb[0]), "=&v"(pb[1]), "=&v"(pb[2]), "=&v"(pb[3]),
        "=&v"(pb[4]), "=&v"(pb[5]), "=&v"(pb[6]), "=&v"(pb[7])
      : "v"(p));
}

static __device__ __forceinline__ unsigned short f2b(float f) {
  union { float f; unsigned int u; } v; v.f = f;
  unsigned int r = v.u + 0x7fffu + ((v.u >> 16) & 1u);   // RNE
  return (unsigned short)(r >> 16);
}
static __device__ __forceinline__ float b2f(unsigned short s) {
  union { unsigned int u; float f; } v; v.u = ((unsigned int)s) << 16; return v.f;
}
static __device__ __forceinline__ unsigned int pk2(float a, float b) {
  return (unsigned int)f2b(a) | ((unsigned int)f2b(b) << 16);
}
static __device__ __forceinline__ float sigm(float x) { return 1.0f / (1.0f + __expf(-x)); }
static __device__ __forceinline__ float tanh_(float x) { return 2.0f / (1.0f + __expf(-2.0f * x)) - 1.0f; }

// --------------------------- group offsets/counts ---------------------------
__global__ void k_offsets(const int* __restrict__ idx, int E,
                          int* __restrict__ offs, int* __restrict__ cnt) {
  int b = blockIdx.x * blockDim.x + threadIdx.x;
  if (b >= NB) return;
  int lo = 0, hi = E;
  while (lo < hi) { int m = (lo + hi) >> 1; if (idx[m] < b) lo = m + 1; else hi = m; }
  int lb = lo;
  lo = lb; hi = E;
  while (lo < hi) { int m = (lo + hi) >> 1; if (idx[m] < b + 1) lo = m + 1; else hi = m; }
  offs[b] = lb;
  cnt[b] = lo - lb;
}

// ------------- per-group stable timestamp rank -> slot permutation ----------
__global__ void k_rank(const float* __restrict__ ts, const int* __restrict__ offs,
                       const int* __restrict__ cnt, int* __restrict__ perm) {
  __shared__ float sts[96];
  int b = blockIdx.x, j = threadIdx.x;
  int o = offs[b];
  int c = cnt[b]; if (c > 96) c = 96;
  if (j < 96) perm[b * 96 + j] = -1;
  if (j < c) sts[j] = ts[o + j];
  __syncthreads();
  if (j < c) {
    float tj = sts[j];
    int rank = 0;
    for (int k = 0; k < c; ++k) {
      float tk = sts[k];
      rank += (tk < tj) || (tk == tj && k < j);
    }
    int slot = (tj > 0.0f ? (96 - c) : 0) + rank;
    perm[b * 96 + slot] = o + j;
  }
}

// ------------- pack 4 weight matrices into MFMA B-fragment order ------------
// value(nt,kt,lane,j) = W[n][k], n = nt*16+(lane&15), k = kt*32+(lane>>4)*8+j
// layout: [mat(4)][nt(48)][kt(8)][lane(64)][j(8)] bf16
__global__ void k_packw(const float* __restrict__ w0, const float* __restrict__ w1,
                        const float* __restrict__ w2, const float* __restrict__ w3,
                        unsigned short* __restrict__ wfrag) {
  int t = blockIdx.x * blockDim.x + threadIdx.x;
  if (t >= 4 * 48 * 8 * 64) return;
  int m = t / 24576;
  int r = t % 24576;
  int nt = r / 512;
  int kt = (r / 64) & 7;
  int lane = r & 63;
  int n = nt * 16 + (lane & 15);
  int kb = kt * 32 + (lane >> 4) * 8;
  const float* W = (m == 0) ? w0 : (m == 1) ? w1 : (m == 2) ? w2 : w3;
  unsigned int o[4];
#pragma unroll
  for (int p = 0; p < 4; ++p)
    o[p] = pk2(W[n * 256 + kb + 2 * p], W[n * 256 + kb + 2 * p + 1]);
  uint4 v; v.x = o[0]; v.y = o[1]; v.z = o[2]; v.w = o[3];
  *(uint4*)&wfrag[(size_t)t * 8] = v;
}

// --------------------------- input-projection GEMM --------------------------
// Round-12 version (validated 163 us): asm-pinned staging, 2 barriers/slab,
// counted vmcnt(4) drain, descending physical slab order.
template <int AMODE>
__launch_bounds__(256, 2)
__global__ void k_xgemm(const float* __restrict__ Ax, const unsigned short* __restrict__ Ab,
                        const int* __restrict__ perm, int t0, int slabsTotal, int jbN,
                        const unsigned short* __restrict__ wfrag, const float* __restrict__ bias,
                        unsigned short* __restrict__ Cout) {
  __shared__ __align__(16) unsigned short lsmA[16640];  // A-frag: 32 regions x 65 x 8 bf16
  __shared__ __align__(16) float lsmS[8960];            // fp32 slab: 64 x 140

  const int tid = threadIdx.x;
  const int ntb = blockIdx.x % 6;
  const int jb  = blockIdx.x / 6;
  if (jb >= slabsTotal) return;
  const int w = tid >> 6, l = tid & 63, lm = l & 15, lq = l >> 4;

  const unsigned short* wfN = wfrag + (size_t)ntb * 32768;
  bh8 bf[2][8];
#pragma unroll
  for (int i = 0; i < 2; ++i)
#pragma unroll
    for (int kt = 0; kt < 8; ++kt)
      gld_b8(bf[i][kt], &wfN[(((2 * w + i) * 8 + kt) * 64 + l) * 8]);
  const float bias0 = bias[ntb * 128 + (2 * w + 0) * 16 + lm];
  const float bias1 = bias[ntb * 128 + (2 * w + 1) * 16 + lm];

  const int trow = tid >> 2, tp = tid & 3;
  const int msub = trow >> 4, rlm = trow & 15;

  f4 pf[16];      // AMODE 0 prefetch (fp32), asm-pinned
  u4v pb[8];      // AMODE 1 prefetch (bf16), asm-pinned

  auto src_of = [&](int s) -> int {   // plain load: PROLOGUE ONLY
    int row = (slabsTotal - 1 - s) * 64 + trow;
    int tt = row >> 11, g = row & 2047;
    return perm[g * 96 + t0 + tt];
  };
  auto issue_pf = [&](int s, int src) {
    if (AMODE == 0) {
      if (src >= 0) {
        gld_pf16(pf, Ax + (size_t)src * 256 + tp * 64);
      } else {
#pragma unroll
        for (int i = 0; i < 16; ++i) pf[i] = (f4){0.f, 0.f, 0.f, 0.f};
      }
    } else {
      int row = (slabsTotal - 1 - s) * 64 + trow;   // descending physical slab
      gld_pb8(pb, Ab + (size_t)row * 256 + tp * 64);
    }
  };
  auto write_afrag = [&]() {
    unsigned short* aN = lsmA;
#pragma unroll
    for (int kk = 0; kk < 2; ++kk)
#pragma unroll
      for (int rlq = 0; rlq < 4; ++rlq) {
        int kt = 2 * tp + kk;
        unsigned short* d = &aN[(((msub * 8 + kt) * 65) + rlq * 16 + rlm) * 8];
        if (AMODE == 0) {
          f4 f0 = pf[8 * kk + 2 * rlq], f1 = pf[8 * kk + 2 * rlq + 1];
          uint4 v;
          v.x = pk2(f0.x, f0.y); v.y = pk2(f0.z, f0.w);
          v.z = pk2(f1.x, f1.y); v.w = pk2(f1.z, f1.w);
          *(uint4*)d = v;
        } else {
          *(u4v*)d = pb[4 * kk + rlq];
        }
      }
  };

  // prologue
  int srcNxt = -1;
  {
    int srcCur = -1;
    if (AMODE == 0) {
      srcCur = src_of(jb);
      if (jb + jbN < slabsTotal) srcNxt = src_of(jb + jbN);
    }
    issue_pf(jb, srcCur);
  }
  vmw<0>(); SCHED0();
  write_afrag();
  LGKM0(); SBAR();

  for (int s = jb; s < slabsTotal; s += jbN) {
    const int snext = s + jbN;
    const bool hasNext = snext < slabsTotal;
    const bool hasNext2 = snext + jbN < slabsTotal;
    int srcN2 = -1;
    if (hasNext) issue_pf(snext, srcNxt);
    if (AMODE == 0 && hasNext2) {
      int row = (slabsTotal - 1 - (snext + jbN)) * 64 + trow;
      int tt2 = row >> 11, g = row & 2047;
      gld_i32(srcN2, &perm[g * 96 + t0 + tt2]);
    }

    // MFMA from lsmA
    f4 acc[4][2];
#pragma unroll
    for (int m = 0; m < 4; ++m)
#pragma unroll
      for (int n = 0; n < 2; ++n) acc[m][n] = (f4){0.f, 0.f, 0.f, 0.f};
#pragma unroll
    for (int kt = 0; kt < 8; ++kt) {
      bh8 a[4];
#pragma unroll
      for (int m = 0; m < 4; ++m) a[m] = *(const bh8*)&lsmA[(((m * 8 + kt) * 65) + l) * 8];
#pragma unroll
      for (int m = 0; m < 4; ++m) {
        acc[m][0] = __builtin_amdgcn_mfma_f32_16x16x32_bf16(a[m], bf[0][kt], acc[m][0], 0, 0, 0);
        acc[m][1] = __builtin_amdgcn_mfma_f32_16x16x32_bf16(a[m], bf[1][kt], acc[m][1], 0, 0, 0);
      }
    }

    // epilogue: acc + bias -> fp32 slab (swizzled: phys = col + 4*(col>>5))
#pragma unroll
    for (int m = 0; m < 4; ++m)
#pragma unroll
      for (int n = 0; n < 2; ++n) {
        int phys = 36 * w + 16 * n + lm;
        float bv = n ? bias1 : bias0;
#pragma unroll
        for (int r = 0; r < 4; ++r)
          lsmS[(m * 16 + lq * 4 + r) * 140 + phys] = acc[m][n][r] + bv;
      }
    LGKM0(); SBAR();

    // merged interval: C-store (reads lsmS) || write_afrag (writes lsmA)
    {
      const float* sp = &lsmS[trow * 140 + 36 * tp];
      unsigned short* cp = &Cout[((size_t)(slabsTotal - 1 - s) * 64 + trow) * NG + ntb * 128 + tp * 32];
#pragma unroll
      for (int i = 0; i < 4; ++i) {
        f4 v0 = *(const f4*)(sp + 8 * i), v1 = *(const f4*)(sp + 8 * i + 4);
        uint4 o;
        o.x = pk2(v0.x, v0.y); o.y = pk2(v0.z, v0.w);
        o.z = pk2(v1.x, v1.y); o.w = pk2(v1.z, v1.w);
        *(uint4*)(cp + 8 * i) = o;
      }
    }
    if (hasNext) {
      // counted drain: queue = [pf x16][perm x<=1][store x4] -> retire
      // pf+perm, leave the 4 C-stores in flight.
      vmw<4>(); SCHED0();
      write_afrag();
      if (AMODE == 0) srcNxt = hasNext2 ? srcN2 : -1;
      LGKM0(); SBAR();
    }
  }
}

// ------------------------------ recurrent core ------------------------------
// Round-12 base (5 plain-loaded weight arrays + lBn) with the round-14
// swizzled-LHA layout: single-half h writes, dup at read (row=l&7 broadcast),
// XOR row^q banks. vm-op accounting identical to round-12:
//   lo / LAYER0: tt=0:4  tt=1:5  2..Ta-4:6  Ta-3:4  Ta-2:2
//   lo / LAYER1: tt=0:4  tt=1:4  2..Ta-4:4  Ta-3:2  Ta-2:0
//   hi (both):   tt=0:2  tt=1:2  2..Ta-4:2  Ta-3:1  Ta-2:0
#define RSTEP(TT, WLO, WHI, ISSUE, H1, WAIT)                                               \
  {                                                                                        \
    if (LAYER == 0 && (H1) && tid < 256) {                                                 \
      int rw_ = tid >> 5, c0_ = (tid & 31) * 8;                                            \
      uint4 hv_ = *(const uint4*)&lh[(TT) & 1][LHA(c0_, rw_)];                             \
      *(uint4*)&h1out[((size_t)((TT) - 1) * NB + g0 + rw_) * DF + c0_] = hv_;              \
    }                                                                                      \
    if (ISSUE) {                                                                           \
      const unsigned short* gp_ = xg + ((size_t)((TT) + 3) * NB + g0) * NG;                \
      unsigned short* lb_ = lxg[((TT) + 3) & 3];                                           \
      gl2lds16(gp_ + (size_t)tid * 8, lb_ + 512 * w);                                      \
      if (tid < 256) gl2lds16(gp_ + 4096 + (size_t)tid * 8, lb_ + 4096 + 512 * w);         \
    }                                                                                      \
    f4 ar0 = (f4){0.f,0.f,0.f,0.f}, ar1 = (f4){0.f,0.f,0.f,0.f};                           \
    f4 az0 = (f4){0.f,0.f,0.f,0.f}, az1 = (f4){0.f,0.f,0.f,0.f};                           \
    f4 an0 = (f4){0.f,0.f,0.f,0.f}, an1 = (f4){0.f,0.f,0.f,0.f};                           \
    {                                                                                      \
      const unsigned short* hc_ = lh[(TT) & 1];                                            \
      _Pragma("unroll")                                                                    \
      for (int kt = 0; kt < 8; ++kt) {                                                     \
        bh8 a_ = *(const bh8*)&hc_[(kt * 64 + lrd) * 8];                                   \
        ar0 = __builtin_amdgcn_mfma_f32_16x16x32_bf16(a_, br0[kt], ar0, 0, 0, 0);          \
        ar1 = __builtin_amdgcn_mfma_f32_16x16x32_bf16(a_, br1[kt], ar1, 0, 0, 0);          \
        az0 = __builtin_amdgcn_mfma_f32_16x16x32_bf16(a_, bz0[kt], az0, 0, 0, 0);          \
        az1 = __builtin_amdgcn_mfma_f32_16x16x32_bf16(a_, bz1[kt], az1, 0, 0, 0);          \
        an0 = __builtin_amdgcn_mfma_f32_16x16x32_bf16(a_, bn0[kt], an0, 0, 0, 0);          \
        bh8 n1_ = *(const bh8*)&lBn[((w * 8 + kt) * 64 + l) * 8];                          \
        an1 = __builtin_amdgcn_mfma_f32_16x16x32_bf16(a_, n1_, an1, 0, 0, 0);              \
      }                                                                                    \
    }                                                                                      \
    {                                                                                      \
      f4 aR = (lq < 2) ? ar0 : ar1;                                                        \
      f4 aZ = (lq < 2) ? az0 : az1;                                                        \
      f4 aN = (lq < 2) ? an0 : an1;                                                        \
      const unsigned short* xc_ = lxg[(TT) & 3];                                           \
      unsigned short* hn_ = lh[((TT) & 1) ^ 1];                                            \
      _Pragma("unroll")                                                                    \
      for (int reg = 0; reg < 4; ++reg) {                                                  \
        int row_ = rlow + reg;                                                             \
        int base_ = row_ * NG + mycol;                                                     \
        float xr_ = b2f(xc_[base_]);                                                       \
        float xz_ = b2f(xc_[base_ + 256]);                                                 \
        float xn_ = b2f(xc_[base_ + 512]);                                                 \
        float r_ = sigm(xr_ + aR[reg] + bhr);                                              \
        float z_ = sigm(xz_ + aZ[reg] + bhz);                                              \
        float n_ = tanh_(xn_ + r_ * (aN[reg] + bhn));                                      \
        float h_ = (1.f - z_) * n_ + z_ * hp[reg]; hp[reg] = h_;                           \
        hn_[LHA(mycol, row_)] = f2b(h_);                                                   \
        if (LAYER == 1) sm[reg] += h_;                                                     \
      }                                                                                    \
    }                                                                                      \
    LGKM0();                                                                               \
    if (WAIT) { if (w < 4) { vmw<(WLO)>(); } else { vmw<(WHI)>(); } }                      \
    SBAR();                                                                                \
  }

template <int LAYER>
__launch_bounds__(512, 2)
__global__ void k_recur(const unsigned short* __restrict__ wf, const float* __restrict__ bhh,
                        const unsigned short* __restrict__ xg, int Ta,
                        float* __restrict__ hstate, int first, int save,
                        unsigned short* __restrict__ h1out,
                        float* __restrict__ sumstate, float* __restrict__ outp, int last) {
  __shared__ __align__(16) unsigned short lBn[32768];     // 64 KB: n ntile 33+2w per wave
  __shared__ __align__(16) unsigned short lh[2][4096];    // 16 KB: h frags, double-buffered
  __shared__ __align__(16) unsigned short lxg[4][6144];   // 48 KB: xg slabs, 4-deep

  const int tid = threadIdx.x;
  const int w = tid >> 6, l = tid & 63, lm = l & 15, lq = l >> 4;
  const int g0 = blockIdx.x * 8;
  const int colA = w * 32 + lm;
  const int mycol = (lq < 2) ? colA : (colA + 16);   // quad-half owns one col
  const int rlow = (lq & 1) * 4;                     // rows rlow..rlow+3
  // A-frag read index: row = l&7 (dup-at-read), region row' = row ^ q:
  const int lrd = (l >> 4) * 16 + (((l & 7) ^ (l >> 4)) & 15);

  // B fragments (plain loads, compiler-managed): r (2), z (2), n (1)
  bh8 br0[8], br1[8], bz0[8], bz1[8], bn0[8];
#pragma unroll
  for (int kt = 0; kt < 8; ++kt) {
    br0[kt] = *(const bh8*)&wf[(((2 * w + 0) * 8 + kt) * 64 + l) * 8];
    br1[kt] = *(const bh8*)&wf[(((2 * w + 1) * 8 + kt) * 64 + l) * 8];
    bz0[kt] = *(const bh8*)&wf[(((16 + 2 * w) * 8 + kt) * 64 + l) * 8];
    bz1[kt] = *(const bh8*)&wf[(((17 + 2 * w) * 8 + kt) * 64 + l) * 8];
    bn0[kt] = *(const bh8*)&wf[(((32 + 2 * w) * 8 + kt) * 64 + l) * 8];
  }
  const float bhr = bhh[mycol];
  const float bhz = bhh[256 + mycol];
  const float bhn = bhh[512 + mycol];

  {  // n ntile 33+2w' -> LDS
    for (int i = tid; i < 4096; i += 512) {
      int wp = i >> 9, kt = (i >> 6) & 7, lane = i & 63;
      ((uint4*)lBn)[i] = *(const uint4*)&wf[(((33 + 2 * wp) * 8 + kt) * 64 + lane) * 8];
    }
  }
  {  // zero both h buffers
    uint4 z; z.x = 0u; z.y = 0u; z.z = 0u; z.w = 0u;
    for (int i = tid; i < 1024; i += 512) ((uint4*)lh)[i] = z;
  }
  __syncthreads();

  float hp[4], sm[4];
#pragma unroll
  for (int reg = 0; reg < 4; ++reg) {
    int row = rlow + reg;
    float a = first ? 0.f : hstate[(size_t)(g0 + row) * DF + mycol];
    hp[reg] = a;
    lh[0][LHA(mycol, row)] = f2b(a);
    if (LAYER == 1) sm[reg] = (!first) ? sumstate[(size_t)(g0 + row) * DF + mycol] : 0.f;
  }
  __syncthreads();

  if (Ta >= 6) {
    // prologue: async-stage xg(0),xg(1),xg(2) into buffers 0,1,2
#pragma unroll
    for (int k = 0; k < 3; ++k) {
      const unsigned short* gp = xg + ((size_t)k * NB + g0) * NG;
      unsigned short* lb = lxg[k];
      gl2lds16(gp + (size_t)tid * 8, lb + 512 * w);
      if (tid < 256) gl2lds16(gp + 4096 + (size_t)tid * 8, lb + 4096 + 512 * w);
    }
    // wait for buf0 (target = oldest pair; newer: g(1),g(2))
    LGKM0();
    if (w < 4) { vmw<4>(); } else { vmw<2>(); }
    SBAR();

    RSTEP(0, 4, 2, true, false, true);
    RSTEP(1, (LAYER == 0 ? 5 : 4), 2, true, true, true);
    for (int tt = 2; tt <= Ta - 4; ++tt) {
      RSTEP(tt, (LAYER == 0 ? 6 : 4), 2, true, true, true);
    }
    RSTEP(Ta - 3, (LAYER == 0 ? 4 : 2), 1, false, true, true);
    RSTEP(Ta - 2, (LAYER == 0 ? 2 : 0), 0, false, true, true);
    RSTEP(Ta - 1, 0, 0, false, true, false);
  } else {
    // generic fallback: conservative vmcnt(0) per step
#pragma unroll
    for (int k = 0; k < 3; ++k) {
      if (k < Ta) {
        const unsigned short* gp = xg + ((size_t)k * NB + g0) * NG;
        unsigned short* lb = lxg[k];
        gl2lds16(gp + (size_t)tid * 8, lb + 512 * w);
        if (tid < 256) gl2lds16(gp + 4096 + (size_t)tid * 8, lb + 4096 + 512 * w);
      }
    }
    LGKM0(); vmw<0>(); SBAR();
    for (int tt = 0; tt < Ta; ++tt) {
      RSTEP(tt, 0, 0, (tt + 3 < Ta), (tt >= 1), (tt + 1 < Ta));
    }
  }

  // final h1out block (h(Ta-1) lives in lh[Ta&1])
  const unsigned short* lhf = lh[Ta & 1];
  if (LAYER == 0 && tid < 256) {
    int row = tid >> 5, c0 = (tid & 31) * 8;
    uint4 hv = *(const uint4*)&lhf[LHA(c0, row)];
    *(uint4*)&h1out[((size_t)(Ta - 1) * NB + g0 + row) * DF + c0] = hv;
  }
  if (save) {
#pragma unroll
    for (int reg = 0; reg < 4; ++reg) {
      int row = rlow + reg;
      hstate[(size_t)(g0 + row) * DF + mycol] = hp[reg];
    }
  }
  if (LAYER == 1) {
    if (last) {
#pragma unroll
      for (int reg = 0; reg < 4; ++reg) {
        int row = rlow + reg;
        outp[(size_t)(g0 + row) * DF + mycol] = sm[reg] * (1.0f / 96.0f);
      }
    } else {
#pragma unroll
      for (int reg = 0; reg < 4; ++reg) {
        int row = rlow + reg;
        sumstate[(size_t)(g0 + row) * DF + mycol] = sm[reg];
      }
    }
  }
}

// ------------------------------- host launcher ------------------------------
extern "C" void kernel_launch(void* const* d_in, const int* in_sizes, int n_in,
                              void* d_out, int out_size, void* d_ws, size_t ws_size,
                              hipStream_t stream) {
  (void)n_in; (void)out_size;
  const float* x    = (const float*)d_in[0];
  const float* ts   = (const float*)d_in[1];
  const float* wih0 = (const float*)d_in[2];
  const float* whh0 = (const float*)d_in[3];
  const float* bih0 = (const float*)d_in[4];
  const float* bhh0 = (const float*)d_in[5];
  const float* wih1 = (const float*)d_in[6];
  const float* whh1 = (const float*)d_in[7];
  const float* bih1 = (const float*)d_in[8];
  const float* bhh1 = (const float*)d_in[9];
  const int*   idx  = (const int*)d_in[10];
  float* out = (float*)d_out;
  const int E = in_sizes[0] / DF;

  char* wsb = (char*)d_ws;
  size_t off = 0;
  auto carve = [&](size_t bytes) -> char* {
    off = (off + 255) & ~(size_t)255;
    char* p = wsb + off;
    off += bytes;
    return p;
  };
  int* offs = (int*)carve((size_t)NB * 4);
  int* cntp = (int*)carve((size_t)NB * 4);
  int* perm = (int*)carve((size_t)NB * LT * 4);
  unsigned short* wfrag = (unsigned short*)carve((size_t)4 * 196608 * 2);
  float* h0s  = (float*)carve((size_t)NB * DF * 4);
  float* h1s  = (float*)carve((size_t)NB * DF * 4);
  float* sums = (float*)carve((size_t)NB * DF * 4);
  size_t fixedBytes = off;

  const size_t perT = (size_t)NB * DF * 2 + 2 * (size_t)NB * NG * 2;  // 7,340,032 B
  int Tc = 1;
  if (ws_size > fixedBytes + 4096) {
    size_t t = (ws_size - fixedBytes - 4096) / perT;
    Tc = (int)(t > 96 ? 96 : (t < 1 ? 1 : t));
  }
  unsigned short* h1buf = (unsigned short*)carve((size_t)Tc * NB * DF * 2);
  unsigned short* xgA   = (unsigned short*)carve((size_t)Tc * NB * NG * 2);
  unsigned short* xgB   = (unsigned short*)carve((size_t)Tc * NB * NG * 2);

  k_offsets<<<8, 256, 0, stream>>>(idx, E, offs, cntp);
  k_rank<<<NB, 128, 0, stream>>>(ts, offs, cntp, perm);
  k_packw<<<384, 256, 0, stream>>>(wih0, whh0, wih1, whh1, wfrag);

  for (int t0 = 0; t0 < LT; t0 += Tc) {
    int Ta = (LT - t0 < Tc) ? (LT - t0) : Tc;
    int first = (t0 == 0);
    int save = (t0 + Ta < LT);
    int last = (t0 + Ta == LT);
    int slabs = Ta * 32;
    // jbN: persistent-block stride; 6*jbN blocks, all co-resident (2/CU)
    int jbN = slabs < 85 ? slabs : 85;
    // layer 0 input projection (gathered x, pads -> b_ih)
    k_xgemm<0><<<dim3(6 * jbN), 256, 0, stream>>>(
        x, (const unsigned short*)nullptr, perm, t0, slabs, jbN, wfrag, bih0, xgA);
    // layer 0 recurrence -> h1buf
    k_recur<0><<<256, 512, 0, stream>>>(
        wfrag + 1 * 196608, bhh0, xgA, Ta, h0s, first, save, h1buf,
        (float*)nullptr, (float*)nullptr, 0);
    // layer 1 input projection (dense h1)
    k_xgemm<1><<<dim3(6 * jbN), 256, 0, stream>>>(
        (const float*)nullptr, h1buf, (const int*)nullptr, 0, slabs, jbN,
        wfrag + 2 * 196608, bih1, xgB);
    // layer 1 recurrence -> mean accumulation / output
    k_recur<1><<<256, 512, 0, stream>>>(
        wfrag + 3 * 196608, bhh1, xgB, Ta, h1s, first, save,
        (unsigned short*)nullptr, sums, out, last);
  }
}

// Round 12
// 935.758 us; speedup vs baseline: 4.4003x; 1.0127x over previous
//
#include <hip/hip_runtime.h>

// ---------------------------------------------------------------------------
// GRUAgg: ragged groups -> dense [B,96,D] (timestamp-sorted, zero-padded head)
// -> 2-layer GRU (PyTorch gate order r,z,n) -> mean over 96 steps.
// B=2048, L=96, D=256, 3D=768, E=131072.
// Round-17: prep-kernel fusion (hot kernels byte-identical to round-16's
// validated 947.6 us build).
//  Evidence: 4 big dispatches sum to ~653 us vs total ~948 -> ~295 us
//  residue, constant across all rounds. Theory split: per-kernel-boundary
//  overhead (7 kernels/launch) vs fixed graph overhead. Test: merge
//  k_offsets+k_rank+k_packw into ONE kernel (k_prep): rank blocks compute
//  their own group's [lb,ub) inline (block-local binary searches, no
//  inter-block dep -> G16-safe), packw runs as blocks 2048..2431 of the
//  same grid. 7 kernels -> 5 per launch. If boundaries ~40us each: -80us.
//  If neutral: residue is fixed overhead -> structure is at its practical
//  ceiling (all surgical levers tried: counted-vmcnt neutral, asm-pin
//  regressed, swizzle neutral, 2-blocks/CU structurally blocked by VGPR).
//  k_xgemm: round-12 version. k_recur: round-12 base + round-14 LHA swizzle.
// ---------------------------------------------------------------------------

typedef short bh8 __attribute__((ext_vector_type(8)));   // 8 bf16 in 4 VGPRs
typedef float f4  __attribute__((ext_vector_type(4)));   // MFMA accumulator
typedef unsigned int u4v __attribute__((ext_vector_type(4)));

#define NB 2048
#define LT 96
#define DF 256
#define NG 768

// h LDS frag layout: [kt(8)][region-swizzled lane][j(8)] bf16.
// element (row,col): q=(col>>3)&3; region=(col>>5)*64 + q*16 + (row^q);
// u16 index = region*8 + (col&7). Banks: ((row^q)%8)*4 -> spread over 32.
#define LHA(col, row) \
  (((((col) >> 5) * 64 + (((col) >> 3) & 3) * 16 + (((row) ^ (((col) >> 3) & 3)) & 15)) * 8) + ((col) & 7))

#define LGKM0()  asm volatile("s_waitcnt lgkmcnt(0)" ::: "memory")
#define SBAR()   __builtin_amdgcn_s_barrier()
#define SCHED0() __builtin_amdgcn_sched_barrier(0)

template <int N>
static __device__ __forceinline__ void vmw() {
  if constexpr (N == 0)      asm volatile("s_waitcnt vmcnt(0)" ::: "memory");
  else if constexpr (N == 1) asm volatile("s_waitcnt vmcnt(1)" ::: "memory");
  else if constexpr (N == 2) asm volatile("s_waitcnt vmcnt(2)" ::: "memory");
  else if constexpr (N == 3) asm volatile("s_waitcnt vmcnt(3)" ::: "memory");
  else if constexpr (N == 4) asm volatile("s_waitcnt vmcnt(4)" ::: "memory");
  else if constexpr (N == 5) asm volatile("s_waitcnt vmcnt(5)" ::: "memory");
  else if constexpr (N == 6) asm volatile("s_waitcnt vmcnt(6)" ::: "memory");
  else                       asm volatile("s_waitcnt vmcnt(7)" ::: "memory");
}

// async global->LDS, 16B per lane; LDS dest is wave-uniform base + lane*16.
static __device__ __forceinline__ void gl2lds16(const void* g, void* l) {
  __builtin_amdgcn_global_load_lds(
      (const __attribute__((address_space(1))) unsigned int*)g,
      (__attribute__((address_space(3))) unsigned int*)l, 16, 0, 0);
}

// Inline-asm loads (k_xgemm staging): immune to IR-level sinking. Every
// consumer sits below an explicit counted vmcnt + sched_barrier(0) fence.
static __device__ __forceinline__ void gld_b8(bh8& d, const unsigned short* p) {
  asm volatile("global_load_dwordx4 %0, %1, off" : "=&v"(d) : "v"(p));
}
static __device__ __forceinline__ void gld_i32(int& d, const int* p) {
  asm volatile("global_load_dword %0, %1, off" : "=&v"(d) : "v"(p));
}
static __device__ __forceinline__ void gld_pf16(f4* pf, const float* p) {
  asm volatile(
      "global_load_dwordx4 %0, %16, off\n\t"
      "global_load_dwordx4 %1, %16, off offset:16\n\t"
      "global_load_dwordx4 %2, %16, off offset:32\n\t"
      "global_load_dwordx4 %3, %16, off offset:48\n\t"
      "global_load_dwordx4 %4, %16, off offset:64\n\t"
      "global_load_dwordx4 %5, %16, off offset:80\n\t"
      "global_load_dwordx4 %6, %16, off offset:96\n\t"
      "global_load_dwordx4 %7, %16, off offset:112\n\t"
      "global_load_dwordx4 %8, %16, off offset:128\n\t"
      "global_load_dwordx4 %9, %16, off offset:144\n\t"
      "global_load_dwordx4 %10, %16, off offset:160\n\t"
      "global_load_dwordx4 %11, %16, off offset:176\n\t"
      "global_load_dwordx4 %12, %16, off offset:192\n\t"
      "global_load_dwordx4 %13, %16, off offset:208\n\t"
      "global_load_dwordx4 %14, %16, off offset:224\n\t"
      "global_load_dwordx4 %15, %16, off offset:240"
      : "=&v"(pf[0]), "=&v"(pf[1]), "=&v"(pf[2]), "=&v"(pf[3]),
        "=&v"(pf[4]), "=&v"(pf[5]), "=&v"(pf[6]), "=&v"(pf[7]),
        "=&v"(pf[8]), "=&v"(pf[9]), "=&v"(pf[10]), "=&v"(pf[11]),
        "=&v"(pf[12]), "=&v"(pf[13]), "=&v"(pf[14]), "=&v"(pf[15])
      : "v"(p));
}
static __device__ __forceinline__ void gld_pb8(u4v* pb, const unsigned short* p) {
  asm volatile(
      "global_load_dwordx4 %0, %8, off\n\t"
      "global_load_dwordx4 %1, %8, off offset:16\n\t"
      "global_load_dwordx4 %2, %8, off offset:32\n\t"
      "global_load_dwordx4 %3, %8, off offset:48\n\t"
      "global_load_dwordx4 %4, %8, off offset:64\n\t"
      "global_load_dwordx4 %5, %8, off offset:80\n\t"
      "global_load_dwordx4 %6, %8, off offset:96\n\t"
      "global_load_dwordx4 %7, %8, off offset:112"
      : "=&v"(pb[0]), "=&v"(pb[1]), "=&v"(pb[2]), "=&v"(pb[3]),
        "=&v"(pb[4]), "=&v"(pb[5]), "=&v"(pb[6]), "=&v"(pb[7])
      : "v"(p));
}

static __device__ __forceinline__ unsigned short f2b(float f) {
  union { float f; unsigned int u; } v; v.f = f;
  unsigned int r = v.u + 0x7fffu + ((v.u >> 16) & 1u);   // RNE
  return (unsigned short)(r >> 16);
}
static __device__ __forceinline__ float b2f(unsigned short s) {
  union { unsigned int u; float f; } v; v.u = ((unsigned int)s) << 16; return v.f;
}
static __device__ __forceinline__ unsigned int pk2(float a, float b) {
  return (unsigned int)f2b(a) | ((unsigned int)f2b(b) << 16);
}
static __device__ __forceinline__ float sigm(float x) { return 1.0f / (1.0f + __expf(-x)); }
static __device__ __forceinline__ float tanh_(float x) { return 2.0f / (1.0f + __expf(-2.0f * x)) - 1.0f; }

// ------------------------- fused prep: rank + packw -------------------------
// Blocks 0..NB-1: per-group timestamp rank -> slot permutation. The group's
// [lb,ub) is computed IN-BLOCK (threads 0/1 each run one binary search over
// idx, LDS broadcast) -- no inter-block dependency (replaces k_offsets).
// Blocks NB..NB+383: weight pack into MFMA B-fragment order
// (value(nt,kt,lane,j) = W[n][k], n=nt*16+(lane&15), k=kt*32+(lane>>4)*8+j;
//  layout [mat(4)][nt(48)][kt(8)][lane(64)][j(8)] bf16).
__global__ void k_prep(const int* __restrict__ idx, int E,
                       const float* __restrict__ ts, int* __restrict__ perm,
                       const float* __restrict__ w0, const float* __restrict__ w1,
                       const float* __restrict__ w2, const float* __restrict__ w3,
                       unsigned short* __restrict__ wfrag) {
  __shared__ float sts[96];
  __shared__ int soc[2];

  if (blockIdx.x < NB) {
    int b = blockIdx.x, j = threadIdx.x;
    if (j < 2) {
      int target = b + j;          // j=0: lower_bound(b); j=1: lower_bound(b+1)
      int lo = 0, hi = E;
      while (lo < hi) { int m = (lo + hi) >> 1; if (idx[m] < target) lo = m + 1; else hi = m; }
      soc[j] = lo;
    }
    __syncthreads();
    int o = soc[0];
    int c = soc[1] - soc[0]; if (c > 96) c = 96;
    if (j < 96) perm[b * 96 + j] = -1;
    if (j < c) sts[j] = ts[o + j];
    __syncthreads();
    if (j < c) {
      float tj = sts[j];
      int rank = 0;
      for (int k = 0; k < c; ++k) {
        float tk = sts[k];
        rank += (tk < tj) || (tk == tj && k < j);
      }
      int slot = (tj > 0.0f ? (96 - c) : 0) + rank;
      perm[b * 96 + slot] = o + j;
    }
  } else {
    int t = (blockIdx.x - NB) * 256 + threadIdx.x;   // 384*256 == 4*48*8*64
    int m = t / 24576;
    int r = t % 24576;
    int nt = r / 512;
    int kt = (r / 64) & 7;
    int lane = r & 63;
    int n = nt * 16 + (lane & 15);
    int kb = kt * 32 + (lane >> 4) * 8;
    const float* W = (m == 0) ? w0 : (m == 1) ? w1 : (m == 2) ? w2 : w3;
    unsigned int o[4];
#pragma unroll
    for (int p = 0; p < 4; ++p)
      o[p] = pk2(W[n * 256 + kb + 2 * p], W[n * 256 + kb + 2 * p + 1]);
    uint4 v; v.x = o[0]; v.y = o[1]; v.z = o[2]; v.w = o[3];
    *(uint4*)&wfrag[(size_t)t * 8] = v;
  }
}

// --------------------------- input-projection GEMM --------------------------
// Round-12 version (validated 163 us): asm-pinned staging, 2 barriers/slab,
// counted vmcnt(4) drain, descending physical slab order.
template <int AMODE>
__launch_bounds__(256, 2)
__global__ void k_xgemm(const float* __restrict__ Ax, const unsigned short* __restrict__ Ab,
                        const int* __restrict__ perm, int t0, int slabsTotal, int jbN,
                        const unsigned short* __restrict__ wfrag, const float* __restrict__ bias,
                        unsigned short* __restrict__ Cout) {
  __shared__ __align__(16) unsigned short lsmA[16640];  // A-frag: 32 regions x 65 x 8 bf16
  __shared__ __align__(16) float lsmS[8960];            // fp32 slab: 64 x 140

  const int tid = threadIdx.x;
  const int ntb = blockIdx.x % 6;
  const int jb  = blockIdx.x / 6;
  if (jb >= slabsTotal) return;
  const int w = tid >> 6, l = tid & 63, lm = l & 15, lq = l >> 4;

  const unsigned short* wfN = wfrag + (size_t)ntb * 32768;
  bh8 bf[2][8];
#pragma unroll
  for (int i = 0; i < 2; ++i)
#pragma unroll
    for (int kt = 0; kt < 8; ++kt)
      gld_b8(bf[i][kt], &wfN[(((2 * w + i) * 8 + kt) * 64 + l) * 8]);
  const float bias0 = bias[ntb * 128 + (2 * w + 0) * 16 + lm];
  const float bias1 = bias[ntb * 128 + (2 * w + 1) * 16 + lm];

  const int trow = tid >> 2, tp = tid & 3;
  const int msub = trow >> 4, rlm = trow & 15;

  f4 pf[16];      // AMODE 0 prefetch (fp32), asm-pinned
  u4v pb[8];      // AMODE 1 prefetch (bf16), asm-pinned

  auto src_of = [&](int s) -> int {   // plain load: PROLOGUE ONLY
    int row = (slabsTotal - 1 - s) * 64 + trow;
    int tt = row >> 11, g = row & 2047;
    return perm[g * 96 + t0 + tt];
  };
  auto issue_pf = [&](int s, int src) {
    if (AMODE == 0) {
      if (src >= 0) {
        gld_pf16(pf, Ax + (size_t)src * 256 + tp * 64);
      } else {
#pragma unroll
        for (int i = 0; i < 16; ++i) pf[i] = (f4){0.f, 0.f, 0.f, 0.f};
      }
    } else {
      int row = (slabsTotal - 1 - s) * 64 + trow;   // descending physical slab
      gld_pb8(pb, Ab + (size_t)row * 256 + tp * 64);
    }
  };
  auto write_afrag = [&]() {
    unsigned short* aN = lsmA;
#pragma unroll
    for (int kk = 0; kk < 2; ++kk)
#pragma unroll
      for (int rlq = 0; rlq < 4; ++rlq) {
        int kt = 2 * tp + kk;
        unsigned short* d = &aN[(((msub * 8 + kt) * 65) + rlq * 16 + rlm) * 8];
        if (AMODE == 0) {
          f4 f0 = pf[8 * kk + 2 * rlq], f1 = pf[8 * kk + 2 * rlq + 1];
          uint4 v;
          v.x = pk2(f0.x, f0.y); v.y = pk2(f0.z, f0.w);
          v.z = pk2(f1.x, f1.y); v.w = pk2(f1.z, f1.w);
          *(uint4*)d = v;
        } else {
          *(u4v*)d = pb[4 * kk + rlq];
        }
      }
  };

  // prologue
  int srcNxt = -1;
  {
    int srcCur = -1;
    if (AMODE == 0) {
      srcCur = src_of(jb);
      if (jb + jbN < slabsTotal) srcNxt = src_of(jb + jbN);
    }
    issue_pf(jb, srcCur);
  }
  vmw<0>(); SCHED0();
  write_afrag();
  LGKM0(); SBAR();

  for (int s = jb; s < slabsTotal; s += jbN) {
    const int snext = s + jbN;
    const bool hasNext = snext < slabsTotal;
    const bool hasNext2 = snext + jbN < slabsTotal;
    int srcN2 = -1;
    if (hasNext) issue_pf(snext, srcNxt);
    if (AMODE == 0 && hasNext2) {
      int row = (slabsTotal - 1 - (snext + jbN)) * 64 + trow;
      int tt2 = row >> 11, g = row & 2047;
      gld_i32(srcN2, &perm[g * 96 + t0 + tt2]);
    }

    // MFMA from lsmA
    f4 acc[4][2];
#pragma unroll
    for (int m = 0; m < 4; ++m)
#pragma unroll
      for (int n = 0; n < 2; ++n) acc[m][n] = (f4){0.f, 0.f, 0.f, 0.f};
#pragma unroll
    for (int kt = 0; kt < 8; ++kt) {
      bh8 a[4];
#pragma unroll
      for (int m = 0; m < 4; ++m) a[m] = *(const bh8*)&lsmA[(((m * 8 + kt) * 65) + l) * 8];
#pragma unroll
      for (int m = 0; m < 4; ++m) {
        acc[m][0] = __builtin_amdgcn_mfma_f32_16x16x32_bf16(a[m], bf[0][kt], acc[m][0], 0, 0, 0);
        acc[m][1] = __builtin_amdgcn_mfma_f32_16x16x32_bf16(a[m], bf[1][kt], acc[m][1], 0, 0, 0);
      }
    }

    // epilogue: acc + bias -> fp32 slab (swizzled: phys = col + 4*(col>>5))
#pragma unroll
    for (int m = 0; m < 4; ++m)
#pragma unroll
      for (int n = 0; n < 2; ++n) {
        int phys = 36 * w + 16 * n + lm;
        float bv = n ? bias1 : bias0;
#pragma unroll
        for (int r = 0; r < 4; ++r)
          lsmS[(m * 16 + lq * 4 + r) * 140 + phys] = acc[m][n][r] + bv;
      }
    LGKM0(); SBAR();

    // merged interval: C-store (reads lsmS) || write_afrag (writes lsmA)
    {
      const float* sp = &lsmS[trow * 140 + 36 * tp];
      unsigned short* cp = &Cout[((size_t)(slabsTotal - 1 - s) * 64 + trow) * NG + ntb * 128 + tp * 32];
#pragma unroll
      for (int i = 0; i < 4; ++i) {
        f4 v0 = *(const f4*)(sp + 8 * i), v1 = *(const f4*)(sp + 8 * i + 4);
        uint4 o;
        o.x = pk2(v0.x, v0.y); o.y = pk2(v0.z, v0.w);
        o.z = pk2(v1.x, v1.y); o.w = pk2(v1.z, v1.w);
        *(uint4*)(cp + 8 * i) = o;
      }
    }
    if (hasNext) {
      // counted drain: queue = [pf x16][perm x<=1][store x4] -> retire
      // pf+perm, leave the 4 C-stores in flight.
      vmw<4>(); SCHED0();
      write_afrag();
      if (AMODE == 0) srcNxt = hasNext2 ? srcN2 : -1;
      LGKM0(); SBAR();
    }
  }
}

// ------------------------------ recurrent core ------------------------------
// Round-12 base (5 plain-loaded weight arrays + lBn) with the round-14
// swizzled-LHA layout: single-half h writes, dup at read (row=l&7 broadcast),
// XOR row^q banks. vm-op accounting identical to round-12:
//   lo / LAYER0: tt=0:4  tt=1:5  2..Ta-4:6  Ta-3:4  Ta-2:2
//   lo / LAYER1: tt=0:4  tt=1:4  2..Ta-4:4  Ta-3:2  Ta-2:0
//   hi (both):   tt=0:2  tt=1:2  2..Ta-4:2  Ta-3:1  Ta-2:0
#define RSTEP(TT, WLO, WHI, ISSUE, H1, WAIT)                                               \
  {                                                                                        \
    if (LAYER == 0 && (H1) && tid < 256) {                                                 \
      int rw_ = tid >> 5, c0_ = (tid & 31) * 8;                                            \
      uint4 hv_ = *(const uint4*)&lh[(TT) & 1][LHA(c0_, rw_)];                             \
      *(uint4*)&h1out[((size_t)((TT) - 1) * NB + g0 + rw_) * DF + c0_] = hv_;              \
    }                                                                                      \
    if (ISSUE) {                                                                           \
      const unsigned short* gp_ = xg + ((size_t)((TT) + 3) * NB + g0) * NG;                \
      unsigned short* lb_ = lxg[((TT) + 3) & 3];                                           \
      gl2lds16(gp_ + (size_t)tid * 8, lb_ + 512 * w);                                      \
      if (tid < 256) gl2lds16(gp_ + 4096 + (size_t)tid * 8, lb_ + 4096 + 512 * w);         \
    }                                                                                      \
    f4 ar0 = (f4){0.f,0.f,0.f,0.f}, ar1 = (f4){0.f,0.f,0.f,0.f};                           \
    f4 az0 = (f4){0.f,0.f,0.f,0.f}, az1 = (f4){0.f,0.f,0.f,0.f};                           \
    f4 an0 = (f4){0.f,0.f,0.f,0.f}, an1 = (f4){0.f,0.f,0.f,0.f};                           \
    {                                                                                      \
      const unsigned short* hc_ = lh[(TT) & 1];                                            \
      _Pragma("unroll")                                                                    \
      for (int kt = 0; kt < 8; ++kt) {                                                     \
        bh8 a_ = *(const bh8*)&hc_[(kt * 64 + lrd) * 8];                                   \
        ar0 = __builtin_amdgcn_mfma_f32_16x16x32_bf16(a_, br0[kt], ar0, 0, 0, 0);          \
        ar1 = __builtin_amdgcn_mfma_f32_16x16x32_bf16(a_, br1[kt], ar1, 0, 0, 0);          \
        az0 = __builtin_amdgcn_mfma_f32_16x16x32_bf16(a_, bz0[kt], az0, 0, 0, 0);          \
        az1 = __builtin_amdgcn_mfma_f32_16x16x32_bf16(a_, bz1[kt], az1, 0, 0, 0);          \
        an0 = __builtin_amdgcn_mfma_f32_16x16x32_bf16(a_, bn0[kt], an0, 0, 0, 0);          \
        bh8 n1_ = *(const bh8*)&lBn[((w * 8 + kt) * 64 + l) * 8];                          \
        an1 = __builtin_amdgcn_mfma_f32_16x16x32_bf16(a_, n1_, an1, 0, 0, 0);              \
      }                                                                                    \
    }                                                                                      \
    {                                                                                      \
      f4 aR = (lq < 2) ? ar0 : ar1;                                                        \
      f4 aZ = (lq < 2) ? az0 : az1;                                                        \
      f4 aN = (lq < 2) ? an0 : an1;                                                        \
      const unsigned short* xc_ = lxg[(TT) & 3];                                           \
      unsigned short* hn_ = lh[((TT) & 1) ^ 1];                                            \
      _Pragma("unroll")                                                                    \
      for (int reg = 0; reg < 4; ++reg) {                                                  \
        int row_ = rlow + reg;                                                             \
        int base_ = row_ * NG + mycol;                                                     \
        float xr_ = b2f(xc_[base_]);                                                       \
        float xz_ = b2f(xc_[base_ + 256]);                                                 \
        float xn_ = b2f(xc_[base_ + 512]);                                                 \
        float r_ = sigm(xr_ + aR[reg] + bhr);                                              \
        float z_ = sigm(xz_ + aZ[reg] + bhz);                                              \
        float n_ = tanh_(xn_ + r_ * (aN[reg] + bhn));                                      \
        float h_ = (1.f - z_) * n_ + z_ * hp[reg]; hp[reg] = h_;                           \
        hn_[LHA(mycol, row_)] = f2b(h_);                                                   \
        if (LAYER == 1) sm[reg] += h_;                                                     \
      }                                                                                    \
    }                                                                                      \
    LGKM0();                                                                               \
    if (WAIT) { if (w < 4) { vmw<(WLO)>(); } else { vmw<(WHI)>(); } }                      \
    SBAR();                                                                                \
  }

template <int LAYER>
__launch_bounds__(512, 2)
__global__ void k_recur(const unsigned short* __restrict__ wf, const float* __restrict__ bhh,
                        const unsigned short* __restrict__ xg, int Ta,
                        float* __restrict__ hstate, int first, int save,
                        unsigned short* __restrict__ h1out,
                        float* __restrict__ sumstate, float* __restrict__ outp, int last) {
  __shared__ __align__(16) unsigned short lBn[32768];     // 64 KB: n ntile 33+2w per wave
  __shared__ __align__(16) unsigned short lh[2][4096];    // 16 KB: h frags, double-buffered
  __shared__ __align__(16) unsigned short lxg[4][6144];   // 48 KB: xg slabs, 4-deep

  const int tid = threadIdx.x;
  const int w = tid >> 6, l = tid & 63, lm = l & 15, lq = l >> 4;
  const int g0 = blockIdx.x * 8;
  const int colA = w * 32 + lm;
  const int mycol = (lq < 2) ? colA : (colA + 16);   // quad-half owns one col
  const int rlow = (lq & 1) * 4;                     // rows rlow..rlow+3
  // A-frag read index: row = l&7 (dup-at-read), region row' = row ^ q:
  const int lrd = (l >> 4) * 16 + (((l & 7) ^ (l >> 4)) & 15);

  // B fragments (plain loads, compiler-managed): r (2), z (2), n (1)
  bh8 br0[8], br1[8], bz0[8], bz1[8], bn0[8];
#pragma unroll
  for (int kt = 0; kt < 8; ++kt) {
    br0[kt] = *(const bh8*)&wf[(((2 * w + 0) * 8 + kt) * 64 + l) * 8];
    br1[kt] = *(const bh8*)&wf[(((2 * w + 1) * 8 + kt) * 64 + l) * 8];
    bz0[kt] = *(const bh8*)&wf[(((16 + 2 * w) * 8 + kt) * 64 + l) * 8];
    bz1[kt] = *(const bh8*)&wf[(((17 + 2 * w) * 8 + kt) * 64 + l) * 8];
    bn0[kt] = *(const bh8*)&wf[(((32 + 2 * w) * 8 + kt) * 64 + l) * 8];
  }
  const float bhr = bhh[mycol];
  const float bhz = bhh[256 + mycol];
  const float bhn = bhh[512 + mycol];

  {  // n ntile 33+2w' -> LDS
    for (int i = tid; i < 4096; i += 512) {
      int wp = i >> 9, kt = (i >> 6) & 7, lane = i & 63;
      ((uint4*)lBn)[i] = *(const uint4*)&wf[(((33 + 2 * wp) * 8 + kt) * 64 + lane) * 8];
    }
  }
  {  // zero both h buffers
    uint4 z; z.x = 0u; z.y = 0u; z.z = 0u; z.w = 0u;
    for (int i = tid; i < 1024; i += 512) ((uint4*)lh)[i] = z;
  }
  __syncthreads();

  float hp[4], sm[4];
#pragma unroll
  for (int reg = 0; reg < 4; ++reg) {
    int row = rlow + reg;
    float a = first ? 0.f : hstate[(size_t)(g0 + row) * DF + mycol];
    hp[reg] = a;
    lh[0][LHA(mycol, row)] = f2b(a);
    if (LAYER == 1) sm[reg] = (!first) ? sumstate[(size_t)(g0 + row) * DF + mycol] : 0.f;
  }
  __syncthreads();

  if (Ta >= 6) {
    // prologue: async-stage xg(0),xg(1),xg(2) into buffers 0,1,2
#pragma unroll
    for (int k = 0; k < 3; ++k) {
      const unsigned short* gp = xg + ((size_t)k * NB + g0) * NG;
      unsigned short* lb = lxg[k];
      gl2lds16(gp + (size_t)tid * 8, lb + 512 * w);
      if (tid < 256) gl2lds16(gp + 4096 + (size_t)tid * 8, lb + 4096 + 512 * w);
    }
    // wait for buf0 (target = oldest pair; newer: g(1),g(2))
    LGKM0();
    if (w < 4) { vmw<4>(); } else { vmw<2>(); }
    SBAR();

    RSTEP(0, 4, 2, true, false, true);
    RSTEP(1, (LAYER == 0 ? 5 : 4), 2, true, true, true);
    for (int tt = 2; tt <= Ta - 4; ++tt) {
      RSTEP(tt, (LAYER == 0 ? 6 : 4), 2, true, true, true);
    }
    RSTEP(Ta - 3, (LAYER == 0 ? 4 : 2), 1, false, true, true);
    RSTEP(Ta - 2, (LAYER == 0 ? 2 : 0), 0, false, true, true);
    RSTEP(Ta - 1, 0, 0, false, true, false);
  } else {
    // generic fallback: conservative vmcnt(0) per step
#pragma unroll
    for (int k = 0; k < 3; ++k) {
      if (k < Ta) {
        const unsigned short* gp = xg + ((size_t)k * NB + g0) * NG;
        unsigned short* lb = lxg[k];
        gl2lds16(gp + (size_t)tid * 8, lb + 512 * w);
        if (tid < 256) gl2lds16(gp + 4096 + (size_t)tid * 8, lb + 4096 + 512 * w);
      }
    }
    LGKM0(); vmw<0>(); SBAR();
    for (int tt = 0; tt < Ta; ++tt) {
      RSTEP(tt, 0, 0, (tt + 3 < Ta), (tt >= 1), (tt + 1 < Ta));
    }
  }

  // final h1out block (h(Ta-1) lives in lh[Ta&1])
  const unsigned short* lhf = lh[Ta & 1];
  if (LAYER == 0 && tid < 256) {
    int row = tid >> 5, c0 = (tid & 31) * 8;
    uint4 hv = *(const uint4*)&lhf[LHA(c0, row)];
    *(uint4*)&h1out[((size_t)(Ta - 1) * NB + g0 + row) * DF + c0] = hv;
  }
  if (save) {
#pragma unroll
    for (int reg = 0; reg < 4; ++reg) {
      int row = rlow + reg;
      hstate[(size_t)(g0 + row) * DF + mycol] = hp[reg];
    }
  }
  if (LAYER == 1) {
    if (last) {
#pragma unroll
      for (int reg = 0; reg < 4; ++reg) {
        int row = rlow + reg;
        outp[(size_t)(g0 + row) * DF + mycol] = sm[reg] * (1.0f / 96.0f);
      }
    } else {
#pragma unroll
      for (int reg = 0; reg < 4; ++reg) {
        int row = rlow + reg;
        sumstate[(size_t)(g0 + row) * DF + mycol] = sm[reg];
      }
    }
  }
}

// ------------------------------- host launcher ------------------------------
extern "C" void kernel_launch(void* const* d_in, const int* in_sizes, int n_in,
                              void* d_out, int out_size, void* d_ws, size_t ws_size,
                              hipStream_t stream) {
  (void)n_in; (void)out_size;
  const float* x    = (const float*)d_in[0];
  const float* ts   = (const float*)d_in[1];
  const float* wih0 = (const float*)d_in[2];
  const float* whh0 = (const float*)d_in[3];
  const float* bih0 = (const float*)d_in[4];
  const float* bhh0 = (const float*)d_in[5];
  const float* wih1 = (const float*)d_in[6];
  const float* whh1 = (const float*)d_in[7];
  const float* bih1 = (const float*)d_in[8];
  const float* bhh1 = (const float*)d_in[9];
  const int*   idx  = (const int*)d_in[10];
  float* out = (float*)d_out;
  const int E = in_sizes[0] / DF;

  char* wsb = (char*)d_ws;
  size_t off = 0;
  auto carve = [&](size_t bytes) -> char* {
    off = (off + 255) & ~(size_t)255;
    char* p = wsb + off;
    off += bytes;
    return p;
  };
  int* perm = (int*)carve((size_t)NB * LT * 4);
  unsigned short* wfrag = (unsigned short*)carve((size_t)4 * 196608 * 2);
  float* h0s  = (float*)carve((size_t)NB * DF * 4);
  float* h1s  = (float*)carve((size_t)NB * DF * 4);
  float* sums = (float*)carve((size_t)NB * DF * 4);
  size_t fixedBytes = off;

  const size_t perT = (size_t)NB * DF * 2 + 2 * (size_t)NB * NG * 2;  // 7,340,032 B
  int Tc = 1;
  if (ws_size > fixedBytes + 4096) {
    size_t t = (ws_size - fixedBytes - 4096) / perT;
    Tc = (int)(t > 96 ? 96 : (t < 1 ? 1 : t));
  }
  unsigned short* h1buf = (unsigned short*)carve((size_t)Tc * NB * DF * 2);
  unsigned short* xgA   = (unsigned short*)carve((size_t)Tc * NB * NG * 2);
  unsigned short* xgB   = (unsigned short*)carve((size_t)Tc * NB * NG * 2);

  // fused prep: rank (blocks 0..NB-1, inline offset search) + packw (384 blocks)
  k_prep<<<NB + 384, 256, 0, stream>>>(idx, E, ts, perm,
                                       wih0, whh0, wih1, whh1, wfrag);

  for (int t0 = 0; t0 < LT; t0 += Tc) {
    int Ta = (LT - t0 < Tc) ? (LT - t0) : Tc;
    int first = (t0 == 0);
    int save = (t0 + Ta < LT);
    int last = (t0 + Ta == LT);
    int slabs = Ta * 32;
    // jbN: persistent-block stride; 6*jbN blocks, all co-resident (2/CU)
    int jbN = slabs < 85 ? slabs : 85;
    // layer 0 input projection (gathered x, pads -> b_ih)
    k_xgemm<0><<<dim3(6 * jbN), 256, 0, stream>>>(
        x, (const unsigned short*)nullptr, perm, t0, slabs, jbN, wfrag, bih0, xgA);
    // layer 0 recurrence -> h1buf
    k_recur<0><<<256, 512, 0, stream>>>(
        wfrag + 1 * 196608, bhh0, xgA, Ta, h0s, first, save, h1buf,
        (float*)nullptr, (float*)nullptr, 0);
    // layer 1 input projection (dense h1)
    k_xgemm<1><<<dim3(6 * jbN), 256, 0, stream>>>(
        (const float*)nullptr, h1buf, (const int*)nullptr, 0, slabs, jbN,
        wfrag + 2 * 196608, bih1, xgB);
    // layer 1 recurrence -> mean accumulation / output
    k_recur<1><<<256, 512, 0, stream>>>(
        wfrag + 3 * 196608, bhh1, xgB, Ta, h1s, first, save,
        (unsigned short*)nullptr, sums, out, last);
  }
}